// Round 8
// baseline (265.946 us; speedup 1.0000x reference)
//
#include <hip/hip_runtime.h>
#include <hip/hip_bf16.h>
#include <math.h>

// Problem dims
#define BATCH 8192
#define INF   1024
#define LEAFW 256
#define OUTF  1024
#define NLEAF 16
#define NNODE 15
#define NTOT  4096      // NLEAF * LEAFW
#define KEXT  4160      // 4096 + 64 (mixture @ B2 folded into GEMM2's K)

typedef __bf16 bf16;
typedef __bf16 bf16x4 __attribute__((ext_vector_type(4)));
typedef __bf16 bf16x8 __attribute__((ext_vector_type(8)));
typedef float  f32x4  __attribute__((ext_vector_type(4)));

// ---------------------------------------------------------------------------
// Merged weight-prep + gating kernel (round-4 version, verbatim; passed).
__global__ __launch_bounds__(256) void prep_gk(
    const float* __restrict__ w1, const float* __restrict__ w2,
    const float* __restrict__ b2s, const float4* __restrict__ x4,
    const float4* __restrict__ nw4, const float* __restrict__ nb,
    bf16* __restrict__ W1T, bf16* __restrict__ W2T, float* __restrict__ mg,
    bf16* __restrict__ Aact, bf16x4* __restrict__ Xbf4) {
  __shared__ float tile[64][65];
  int b = blockIdx.x;
  int t = threadIdx.x;

  if (b < 2048) {  // ---- 64x64 transpose (w1 or w2) ----
    const float* src;
    bf16* dst;
    int srcld, dstld, r0, c0;
    if (b < 1024) {
      int l = b >> 6, rem = b & 63;
      r0 = (rem >> 2) * 64;
      c0 = (rem & 3) * 64;
      src = w1 + (size_t)l * INF * LEAFW;
      srcld = LEAFW;
      dst = W1T + (size_t)l * LEAFW * INF;
      dstld = INF;
    } else {
      int bb = b - 1024;
      int l = bb >> 6, rem = bb & 63;
      r0 = (rem >> 4) * 64;
      c0 = (rem & 15) * 64;
      src = w2 + (size_t)l * LEAFW * OUTF;
      srcld = OUTF;
      dst = W2T + l * LEAFW;
      dstld = KEXT;
    }
    int fr = t >> 4, hc4 = (t & 15) * 4;
#pragma unroll
    for (int p = 0; p < 4; ++p) {
      float4 v = *reinterpret_cast<const float4*>(
          &src[(size_t)(r0 + fr + p * 16) * srcld + c0 + hc4]);
      tile[fr + p * 16][hc4 + 0] = v.x;
      tile[fr + p * 16][hc4 + 1] = v.y;
      tile[fr + p * 16][hc4 + 2] = v.z;
      tile[fr + p * 16][hc4 + 3] = v.w;
    }
    __syncthreads();
#pragma unroll
    for (int p = 0; p < 2; ++p) {
      int s = t + p * 256;
      int h = s >> 3, fc = (s & 7) * 8;
      bf16x8 o;
#pragma unroll
      for (int e = 0; e < 8; ++e) o[e] = (bf16)tile[fc + e][h];
      *reinterpret_cast<bf16x8*>(&dst[(size_t)(c0 + h) * dstld + r0 + fc]) = o;
    }
    return;
  }

  if (b < 2304) {  // ---- W2T extension columns ----
    int i = (b - 2048) * 256 + t;
    int o = i >> 6, j = i & 63;
    W2T[(size_t)o * KEXT + NTOT + j] =
        (j < NLEAF) ? (bf16)b2s[(size_t)j * OUTF + o] : (bf16)0.f;
    return;
  }

  // ---- gating: one wave per row ----
  int row  = (b - 2304) * 4 + (t >> 6);
  int lane = t & 63;
  const float4* xr4 = x4 + (size_t)row * (INF / 4);

  float p[NNODE];
#pragma unroll
  for (int j = 0; j < NNODE; ++j) p[j] = 0.f;
#pragma unroll
  for (int c = 0; c < INF / 256; ++c) {
    int idx = c * 64 + lane;
    float4 xv = xr4[idx];
#pragma unroll
    for (int j = 0; j < NNODE; ++j) {
      float4 wv = nw4[j * (INF / 4) + idx];
      p[j] += xv.x * wv.x + xv.y * wv.y + xv.z * wv.z + xv.w * wv.w;
    }
    bf16x4 o = {(bf16)xv.x, (bf16)xv.y, (bf16)xv.z, (bf16)xv.w};
    Xbf4[(size_t)row * (INF / 4) + idx] = o;
  }
#pragma unroll
  for (int j = 0; j < NNODE; ++j) {
    float v = p[j];
#pragma unroll
    for (int off = 32; off > 0; off >>= 1) v += __shfl_xor(v, off);
    p[j] = 1.f / (1.f + expf(-(v + nb[j])));
  }
  float mixv[NLEAF];
#pragma unroll
  for (int L = 0; L < NLEAF; ++L) {
    int n1 = 1 + (L >> 3), n2 = 3 + (L >> 2), n3 = 7 + (L >> 1);
    float m = ((L >> 3) & 1) ? p[0] : (1.f - p[0]);
    m *= ((L >> 2) & 1) ? p[n1] : (1.f - p[n1]);
    m *= ((L >> 1) & 1) ? p[n2] : (1.f - p[n2]);
    m *= (L & 1) ? p[n3] : (1.f - p[n3]);
    mixv[L] = m;
  }
  bf16* arow = Aact + (size_t)row * KEXT + NTOT;
  if (lane == 0) {
#pragma unroll
    for (int L = 0; L < NLEAF; ++L) {
      mg[row * NLEAF + L] = mixv[L];
      arow[L] = (bf16)mixv[L];
    }
  }
  if (lane >= 16) arow[lane] = (bf16)0.f;
}

// ---------------------------------------------------------------------------
template <int N>
__device__ __forceinline__ void wait_vmcnt() {
  asm volatile("s_waitcnt vmcnt(%0)" ::"n"(N) : "memory");
}
__device__ __forceinline__ void barrier_fence() {
  asm volatile("" ::: "memory");
  __builtin_amdgcn_s_barrier();
  asm volatile("" ::: "memory");
}

// ---------------------------------------------------------------------------
// GEMM1 persistent: 256 blocks (1/CU), each owns one n-panel (bn fixed) and
// walks 4 consecutive 128-row m-tiles with ONE continuous 2-phase pipeline
// (64 virtual K-steps). Inner loop identical to the round-3/7 2-phase
// structure (P0: read A+B0, stage next {A,B0}, 16 MFMA, vmcnt(4), barrier;
// P1: read B1, stage next B1, 16 MFMA, vmcnt(2), barrier). At the 3 interior
// tile boundaries: inline epilogue for the finished tile, zero acc, then
// vmcnt(0)+barrier re-anchors the counted-vmcnt invariants (each wave drains
// its own loads/stores; barrier publishes all staged LDS).
// Mapping: xcd = orig&7 owns m-groups {2*xcd, 2*xcd+1} (2 MB A, L2-resident);
// n = idx&15 (B panels shared across XCDs, L3-served).
__global__ __launch_bounds__(512, 2) void g1_pers(
    const bf16* __restrict__ A, const bf16* __restrict__ BT,
    const float* __restrict__ bias, const float* __restrict__ mg,
    bf16* __restrict__ outB) {
  constexpr int NS  = 64;         // virtual steps: 4 tiles x 16 K-tiles
  constexpr int ASZ = 128 * 64;   // elems per A buf (16 KiB)
  constexpr int BSZ = 256 * 64;   // elems per B buf (32 KiB)
  __shared__ __align__(16) bf16 As[2 * ASZ];
  __shared__ __align__(16) bf16 Bs[2 * BSZ];

  const int t = threadIdx.x, lane = t & 63, w = t >> 6;
  const int wm = w >> 2, wn = w & 3;
  const int orig = blockIdx.x;           // 256 blocks
  const int xcd  = orig & 7, idx = orig >> 3;  // idx in [0,32)
  const int bn   = (idx & 15) * 256;           // n-panel (fixed)
  const int bm0  = (xcd * 2 + (idx >> 4)) * 512;  // m-group base (4 tiles)
  const int lr = t >> 3, cs = t & 7;
  const int scol = ((cs ^ (lr & 7)) << 3);  // XOR pre-swizzled global col

  auto stageA = [&](int vbm, int kt, int buf) {
#pragma unroll
    for (int q = 0; q < 2; ++q) {
      const bf16* src = A + (size_t)(vbm + q * 64 + lr) * INF + kt * 64 + scol;
      __builtin_amdgcn_global_load_lds(
          (const __attribute__((address_space(1))) void*)src,
          (__attribute__((address_space(3))) void*)((char*)As +
                                                    buf * (ASZ * 2) +
                                                    q * 8192 + t * 16),
          16, 0, 0);
    }
  };
  auto stageB = [&](int kt, int h, int buf) {
#pragma unroll
    for (int q = 0; q < 2; ++q) {
      const bf16* src =
          BT + (size_t)(bn + h * 128 + q * 64 + lr) * INF + kt * 64 + scol;
      __builtin_amdgcn_global_load_lds(
          (const __attribute__((address_space(1))) void*)src,
          (__attribute__((address_space(3))) void*)((char*)Bs +
                                                    buf * (BSZ * 2) +
                                                    h * 16384 + q * 8192 +
                                                    t * 16),
          16, 0, 0);
    }
  };
  auto rdA = [&](int buf, int i, int kk) -> bf16x8 {
    int r  = (i >> 1) * 64 + wm * 32 + (i & 1) * 16 + (lane & 15);
    int ch = ((kk << 2) + (lane >> 4)) ^ (lane & 7);
    return *reinterpret_cast<const bf16x8*>(&As[buf * ASZ + r * 64 + ch * 8]);
  };
  auto rdB = [&](int buf, int j, int kk) -> bf16x8 {
    int r  = wn * 32 + (j & 1) * 16 + (lane & 15);
    int ch = ((kk << 2) + (lane >> 4)) ^ (lane & 7);
    return *reinterpret_cast<const bf16x8*>(
        &Bs[buf * BSZ + (j >> 1) * 8192 + r * 64 + ch * 8]);
  };

  f32x4 acc[4][4];
#pragma unroll
  for (int i = 0; i < 4; ++i)
#pragma unroll
    for (int j = 0; j < 4; ++j) acc[i][j] = (f32x4){0.f, 0.f, 0.f, 0.f};

  const int leaf = bn >> 8;  // constant per block

  // Prologue: step0 {A,B0,B1}; vmcnt(2) leaves B1 in flight.
  stageA(bm0, 0, 0);
  stageB(0, 0, 0);
  stageB(0, 1, 0);
  wait_vmcnt<2>();
  barrier_fence();

  for (int s = 0; s < NS; ++s) {
    const int cur = s & 1, nxt = cur ^ 1;
    const int u   = (s + 1 < NS) ? s + 1 : NS - 1;  // clamp keeps counts
    const int ukt = u & 15;
    const int ubm = bm0 + (u >> 4) * 128;
    bf16x8 af[4][2], bq0[2][2], bq1[2][2];

    // ---- P0: read A,B0; stage step-u {A,B0}; MFMA N-half 0
#pragma unroll
    for (int i = 0; i < 4; ++i)
#pragma unroll
      for (int kk = 0; kk < 2; ++kk) af[i][kk] = rdA(cur, i, kk);
#pragma unroll
    for (int j = 0; j < 2; ++j)
#pragma unroll
      for (int kk = 0; kk < 2; ++kk) bq0[j][kk] = rdB(cur, j, kk);
    stageA(ubm, ukt, nxt);
    stageB(ukt, 0, nxt);
    __builtin_amdgcn_s_setprio(1);
#pragma unroll
    for (int kk = 0; kk < 2; ++kk)
#pragma unroll
      for (int i = 0; i < 4; ++i)
#pragma unroll
        for (int j = 0; j < 2; ++j)
          acc[i][j] = __builtin_amdgcn_mfma_f32_16x16x32_bf16(
              af[i][kk], bq0[j][kk], acc[i][j], 0, 0, 0);
    __builtin_amdgcn_s_setprio(0);
    wait_vmcnt<4>();
    barrier_fence();

    // ---- P1: read B1; stage step-u B1; MFMA N-half 1
#pragma unroll
    for (int j = 0; j < 2; ++j)
#pragma unroll
      for (int kk = 0; kk < 2; ++kk) bq1[j][kk] = rdB(cur, 2 + j, kk);
    stageB(ukt, 1, nxt);
    __builtin_amdgcn_s_setprio(1);
#pragma unroll
    for (int kk = 0; kk < 2; ++kk)
#pragma unroll
      for (int i = 0; i < 4; ++i)
#pragma unroll
        for (int j = 0; j < 2; ++j)
          acc[i][2 + j] = __builtin_amdgcn_mfma_f32_16x16x32_bf16(
              af[i][kk], bq1[j][kk], acc[i][2 + j], 0, 0, 0);
    __builtin_amdgcn_s_setprio(0);
    wait_vmcnt<2>();
    barrier_fence();

    // ---- tile boundary: epilogue for finished tile, reset acc, re-anchor
    if ((s & 15) == 15) {
      const int tbm = bm0 + (s >> 4) * 128;
#pragma unroll
      for (int i = 0; i < 4; ++i) {
        int rb =
            tbm + (i >> 1) * 64 + wm * 32 + (i & 1) * 16 + ((lane >> 4) << 2);
#pragma unroll
        for (int rr = 0; rr < 4; ++rr) {
          const int grow = rb + rr;
          const float g  = mg[grow * NLEAF + leaf];
#pragma unroll
          for (int j = 0; j < 4; ++j) {
            const int gcol =
                bn + (j >> 1) * 128 + wn * 32 + (j & 1) * 16 + (lane & 15);
            float v = acc[i][j][rr] + bias[gcol];
            v = v > 0.f ? v : 0.f;
            outB[(size_t)grow * KEXT + gcol] = (bf16)(v * g);
          }
        }
      }
#pragma unroll
      for (int i = 0; i < 4; ++i)
#pragma unroll
        for (int j = 0; j < 4; ++j) acc[i][j] = (f32x4){0.f, 0.f, 0.f, 0.f};
      wait_vmcnt<0>();  // drain stores + in-flight stages; reset invariants
      barrier_fence();
    }
  }
}

// ---------------------------------------------------------------------------
// GEMM2 (round-7 version, verbatim; passed): 128x256 tile, 2-phase
// counted-vmcnt, fp32 out.
__global__ __launch_bounds__(512, 2) void gemm2_kernel(
    const bf16* __restrict__ A, const bf16* __restrict__ BT,
    float* __restrict__ outF) {
  constexpr int NT  = KEXT / 64;  // 65
  constexpr int ASZ = 128 * 64;
  constexpr int BSZ = 256 * 64;
  __shared__ __align__(16) bf16 As[2 * ASZ];
  __shared__ __align__(16) bf16 Bs[2 * BSZ];

  const int t = threadIdx.x, lane = t & 63, w = t >> 6;
  const int wm = w >> 2, wn = w & 3;
  const int orig = blockIdx.x;
  const int swz  = (orig & 7) * 32 + (orig >> 3);  // 256 blocks
  const int bm = (swz >> 2) * 128, bn = (swz & 3) * 256;
  const int lr = t >> 3, cs = t & 7;
  const int scol = ((cs ^ (lr & 7)) << 3);

  auto stageA = [&](int kt, int buf) {
#pragma unroll
    for (int q = 0; q < 2; ++q) {
      const bf16* src = A + (size_t)(bm + q * 64 + lr) * KEXT + kt * 64 + scol;
      __builtin_amdgcn_global_load_lds(
          (const __attribute__((address_space(1))) void*)src,
          (__attribute__((address_space(3))) void*)((char*)As +
                                                    buf * (ASZ * 2) +
                                                    q * 8192 + t * 16),
          16, 0, 0);
    }
  };
  auto stageB = [&](int kt, int h, int buf) {
#pragma unroll
    for (int q = 0; q < 2; ++q) {
      const bf16* src =
          BT + (size_t)(bn + h * 128 + q * 64 + lr) * KEXT + kt * 64 + scol;
      __builtin_amdgcn_global_load_lds(
          (const __attribute__((address_space(1))) void*)src,
          (__attribute__((address_space(3))) void*)((char*)Bs +
                                                    buf * (BSZ * 2) +
                                                    h * 16384 + q * 8192 +
                                                    t * 16),
          16, 0, 0);
    }
  };
  auto rdA = [&](int buf, int i, int kk) -> bf16x8 {
    int r  = (i >> 1) * 64 + wm * 32 + (i & 1) * 16 + (lane & 15);
    int ch = ((kk << 2) + (lane >> 4)) ^ (lane & 7);
    return *reinterpret_cast<const bf16x8*>(&As[buf * ASZ + r * 64 + ch * 8]);
  };
  auto rdB = [&](int buf, int j, int kk) -> bf16x8 {
    int r  = wn * 32 + (j & 1) * 16 + (lane & 15);
    int ch = ((kk << 2) + (lane >> 4)) ^ (lane & 7);
    return *reinterpret_cast<const bf16x8*>(
        &Bs[buf * BSZ + (j >> 1) * 8192 + r * 64 + ch * 8]);
  };

  f32x4 acc[4][4];
#pragma unroll
  for (int i = 0; i < 4; ++i)
#pragma unroll
    for (int j = 0; j < 4; ++j) acc[i][j] = (f32x4){0.f, 0.f, 0.f, 0.f};

  stageA(0, 0);
  stageB(0, 0, 0);
  stageB(0, 1, 0);
  wait_vmcnt<2>();
  barrier_fence();

  for (int kt = 0; kt < NT; ++kt) {
    const int cur = kt & 1, nxt = cur ^ 1;
    const int k1 = kt + 1 < NT ? kt + 1 : NT - 1;
    bf16x8 af[4][2], bq0[2][2], bq1[2][2];

#pragma unroll
    for (int i = 0; i < 4; ++i)
#pragma unroll
      for (int kk = 0; kk < 2; ++kk) af[i][kk] = rdA(cur, i, kk);
#pragma unroll
    for (int j = 0; j < 2; ++j)
#pragma unroll
      for (int kk = 0; kk < 2; ++kk) bq0[j][kk] = rdB(cur, j, kk);
    stageA(k1, nxt);
    stageB(k1, 0, nxt);
    __builtin_amdgcn_s_setprio(1);
#pragma unroll
    for (int kk = 0; kk < 2; ++kk)
#pragma unroll
      for (int i = 0; i < 4; ++i)
#pragma unroll
        for (int j = 0; j < 2; ++j)
          acc[i][j] = __builtin_amdgcn_mfma_f32_16x16x32_bf16(
              af[i][kk], bq0[j][kk], acc[i][j], 0, 0, 0);
    __builtin_amdgcn_s_setprio(0);
    wait_vmcnt<4>();
    barrier_fence();

#pragma unroll
    for (int j = 0; j < 2; ++j)
#pragma unroll
      for (int kk = 0; kk < 2; ++kk) bq1[j][kk] = rdB(cur, 2 + j, kk);
    stageB(k1, 1, nxt);
    __builtin_amdgcn_s_setprio(1);
#pragma unroll
    for (int kk = 0; kk < 2; ++kk)
#pragma unroll
      for (int i = 0; i < 4; ++i)
#pragma unroll
        for (int j = 0; j < 2; ++j)
          acc[i][2 + j] = __builtin_amdgcn_mfma_f32_16x16x32_bf16(
              af[i][kk], bq1[j][kk], acc[i][2 + j], 0, 0, 0);
    __builtin_amdgcn_s_setprio(0);
    wait_vmcnt<2>();
    barrier_fence();
  }

#pragma unroll
  for (int i = 0; i < 4; ++i) {
    int rb = bm + (i >> 1) * 64 + wm * 32 + (i & 1) * 16 + ((lane >> 4) << 2);
#pragma unroll
    for (int rr = 0; rr < 4; ++rr) {
      const int grow = rb + rr;
#pragma unroll
      for (int j = 0; j < 4; ++j) {
        const int gcol =
            bn + (j >> 1) * 128 + wn * 32 + (j & 1) * 16 + (lane & 15);
        outF[(size_t)grow * OUTF + gcol] = acc[i][j][rr];
      }
    }
  }
}

// ---------------------------------------------------------------------------
extern "C" void kernel_launch(void* const* d_in, const int* in_sizes, int n_in,
                              void* d_out, int out_size, void* d_ws,
                              size_t ws_size, hipStream_t stream) {
  const float* x   = (const float*)d_in[0];
  const float* nw  = (const float*)d_in[1];
  const float* nb  = (const float*)d_in[2];
  const float* w1s = (const float*)d_in[3];
  const float* b1s = (const float*)d_in[4];
  const float* w2s = (const float*)d_in[5];
  const float* b2s = (const float*)d_in[6];
  float* out = (float*)d_out;

  char* ws = (char*)d_ws;
  bf16*  Xbf  = (bf16*)(ws);                  // 16,777,216 B
  bf16*  W1T  = (bf16*)(ws + 16777216);       //  8,388,608 B  [4096][1024]
  bf16*  W2T  = (bf16*)(ws + 25165824);       //  8,519,680 B  [1024][4160]
  float* mg   = (float*)(ws + 33685504);      //    524,288 B  [8192][16]
  bf16*  Aact = (bf16*)(ws + 34209792);       // 68,157,440 B  [8192][4160]

  prep_gk<<<dim3(4352), 256, 0, stream>>>(
      w1s, w2s, b2s, (const float4*)x, (const float4*)nw, nb, W1T, W2T, mg,
      Aact, (bf16x4*)Xbf);

  // GEMM1 persistent: 256 blocks (1/CU), 4 m-tiles each, continuous pipeline
  g1_pers<<<dim3(256), 512, 0, stream>>>(Xbf, W1T, b1s, mg, Aact);
  // GEMM2: 128x256 tile, grid 64*4 = 256 blocks, 2-phase
  gemm2_kernel<<<dim3(256), 512, 0, stream>>>(Aact, W2T, out);
}